// Round 1
// baseline (145.655 us; speedup 1.0000x reference)
//
#include <hip/hip_runtime.h>

static constexpr int Vn = 1024;   // codebook size
static constexpr int Dn = 256;    // code dim
static constexpr int NT = 65536;  // B * TOK

// ---------------------------------------------------------------------------
// Kernel 1: G = W * W^T  (1024 x 1024, K = 256), fp32 LDS-tiled 64x64.
// 0.27 G-MACs total -> a few microseconds; fp32 to keep argmin margins exact.
// ---------------------------------------------------------------------------
__global__ __launch_bounds__(256) void gram_kernel(const float* __restrict__ W,
                                                   float* __restrict__ G) {
    __shared__ float As[16][65];  // [k][m], +1 pad breaks bank conflicts
    __shared__ float Bs[16][65];
    const int tid = threadIdx.x;
    const int tx = tid & 15;   // micro-tile col group
    const int ty = tid >> 4;   // micro-tile row group
    const int bm = blockIdx.y * 64;
    const int bn = blockIdx.x * 64;
    float acc[4][4] = {};
    for (int k0 = 0; k0 < Dn; k0 += 16) {
#pragma unroll
        for (int s = 0; s < 4; ++s) {
            int e = tid + 256 * s;
            int m = e >> 4;
            int k = e & 15;
            As[k][m] = W[(bm + m) * Dn + k0 + k];
            Bs[k][m] = W[(bn + m) * Dn + k0 + k];
        }
        __syncthreads();
#pragma unroll
        for (int kk = 0; kk < 16; ++kk) {
            float a[4], b[4];
#pragma unroll
            for (int u = 0; u < 4; ++u) a[u] = As[kk][ty * 4 + u];
#pragma unroll
            for (int u = 0; u < 4; ++u) b[u] = Bs[kk][tx * 4 + u];
#pragma unroll
            for (int u = 0; u < 4; ++u)
#pragma unroll
                for (int w = 0; w < 4; ++w)
                    acc[u][w] = fmaf(a[u], b[w], acc[u][w]);
        }
        __syncthreads();
    }
#pragma unroll
    for (int u = 0; u < 4; ++u) {
        const int row = bm + ty * 4 + u;
#pragma unroll
        for (int w = 0; w < 4; ++w) {
            G[row * Vn + bn + tx * 4 + w] = acc[u][w];
        }
    }
}

// ---------------------------------------------------------------------------
// Kernel 2: norms[v] = G[v][v] = ||w_v||^2
// ---------------------------------------------------------------------------
__global__ void diag_kernel(const float* __restrict__ G, float* __restrict__ norms) {
    const int v = blockIdx.x * 256 + threadIdx.x;
    norms[v] = G[v * (Vn + 1)];
}

// ---------------------------------------------------------------------------
// Kernel 3: per-token argmin over V codes.
//   score(v) = norms[v] - 2(1-a) G[i,v] - 2a G[j,v]   (||x||^2 dropped)
// One wave per token, 4 tokens per wave; 256 threads = 16 tokens/block so the
// 4 KB norms LDS stage is amortized 16x. float4 loads of G rows (L2 hits).
// Lexicographic (score, v) reduce reproduces jnp.argmin first-min tie-break.
// ---------------------------------------------------------------------------
__global__ __launch_bounds__(256) void argmin_kernel(const int* __restrict__ seq,
                                                     const int* __restrict__ seq2,
                                                     const float* __restrict__ alpha,
                                                     const float* __restrict__ G,
                                                     const float* __restrict__ norms,
                                                     int* __restrict__ out_idx) {
    __shared__ float nrm[Vn];
    const int tid = threadIdx.x;
    {   // stage norms: 256 threads x 16 B = 4 KB
        const float4* n4 = (const float4*)norms;
        float4* s4 = (float4*)nrm;
        s4[tid] = n4[tid];
    }
    __syncthreads();
    const float a = alpha[0];
    const float c0 = -2.0f * (1.0f - a);
    const float c1 = -2.0f * a;
    const int wave = tid >> 6;
    const int lane = tid & 63;
    const int base_t = blockIdx.x * 16 + wave * 4;
    const float4* nr = (const float4*)nrm;
    for (int q = 0; q < 4; ++q) {
        const int t = base_t + q;
        const int i = seq[t];
        const int j = seq2[t];
        const float4* Gi = (const float4*)(G + i * Vn);
        const float4* Gj = (const float4*)(G + j * Vn);
        float best = __builtin_inff();
        int bestV = 0;
#pragma unroll
        for (int s = 0; s < 4; ++s) {
            const int e = s * 64 + lane;  // float4 index; v = 4e..4e+3 (ascending per lane)
            const float4 gi = Gi[e];
            const float4 gj = Gj[e];
            const float4 nn = nr[e];
            const float sc0 = fmaf(c1, gj.x, fmaf(c0, gi.x, nn.x));
            const float sc1 = fmaf(c1, gj.y, fmaf(c0, gi.y, nn.y));
            const float sc2 = fmaf(c1, gj.z, fmaf(c0, gi.z, nn.z));
            const float sc3 = fmaf(c1, gj.w, fmaf(c0, gi.w, nn.w));
            const int v = e * 4;
            // strict < keeps the smallest v within this lane's ascending sequence
            if (sc0 < best) { best = sc0; bestV = v; }
            if (sc1 < best) { best = sc1; bestV = v + 1; }
            if (sc2 < best) { best = sc2; bestV = v + 2; }
            if (sc3 < best) { best = sc3; bestV = v + 3; }
        }
        // 64-lane butterfly-style reduce, lexicographic on (score, v)
#pragma unroll
        for (int off = 32; off >= 1; off >>= 1) {
            const float ob = __shfl_down(best, off, 64);
            const int   ov = __shfl_down(bestV, off, 64);
            if (ob < best || (ob == best && ov < bestV)) { best = ob; bestV = ov; }
        }
        if (lane == 0) out_idx[t] = bestV;
    }
}

// ---------------------------------------------------------------------------
// Kernel 4: out[b, d, h, w] = W[idx[b*256 + h*16 + w], d]
// 32x32 LDS-transpose tiles: reads 128 B contiguous per half-wave from W rows,
// writes 128 B contiguous to out. +1 pad kills bank conflicts.
// ---------------------------------------------------------------------------
__global__ __launch_bounds__(256) void gather_transpose_kernel(const float* __restrict__ W,
                                                               const int* __restrict__ idx,
                                                               float* __restrict__ out) {
    __shared__ float tile[32][33];
    const int b   = blockIdx.z;
    const int hw0 = blockIdx.x * 32;
    const int d0  = blockIdx.y * 32;
    const int tx  = threadIdx.x & 31;
    const int ty  = threadIdx.x >> 5;  // 0..7
#pragma unroll
    for (int r = ty; r < 32; r += 8) {
        const int row = idx[b * 256 + hw0 + r];
        tile[r][tx] = W[row * Dn + d0 + tx];
    }
    __syncthreads();
#pragma unroll
    for (int r = ty; r < 32; r += 8) {
        out[b * 65536 + (d0 + r) * 256 + hw0 + tx] = tile[tx][r];
    }
}

// ---------------------------------------------------------------------------
extern "C" void kernel_launch(void* const* d_in, const int* in_sizes, int n_in,
                              void* d_out, int out_size, void* d_ws, size_t ws_size,
                              hipStream_t stream) {
    const int*   seq   = (const int*)d_in[0];    // [256,256] int32
    const int*   seq2  = (const int*)d_in[1];    // [256,256] int32
    const float* alpha = (const float*)d_in[2];  // [1]
    const float* W     = (const float*)d_in[3];  // [1024,256] f32
    float* out = (float*)d_out;                  // [256,256,16,16] f32

    char* ws = (char*)d_ws;
    float* G     = (float*)ws;                                    // 4 MB
    float* norms = (float*)(ws + (size_t)Vn * Vn * 4);            // 4 KB
    int*   idx   = (int*)(ws + (size_t)Vn * Vn * 4 + Vn * 4);     // 256 KB

    gram_kernel<<<dim3(16, 16), 256, 0, stream>>>(W, G);
    diag_kernel<<<Vn / 256, 256, 0, stream>>>(G, norms);
    argmin_kernel<<<NT / 16, 256, 0, stream>>>(seq, seq2, alpha, G, norms, idx);
    gather_transpose_kernel<<<dim3(8, 8, 256), 256, 0, stream>>>(W, idx, out);
}